// Round 10
// baseline (242.919 us; speedup 1.0000x reference)
//
#include <hip/hip_runtime.h>
#include <hip/hip_bf16.h>

#define DM 256
#define SEQ 4096
#define XSTR 528   // x/qa row stride bytes (132 dwords, 4-bank rotate/row)
#define TSTR 72    // kA transpose tile row stride bytes (18 dwords -> 16 distinct banks/16 lanes)

typedef __attribute__((ext_vector_type(8))) short bf16x8;
typedef __attribute__((ext_vector_type(4))) float f32x4;

#define MFMA16(a, b, c) __builtin_amdgcn_mfma_f32_16x16x32_bf16(a, b, c, 0, 0, 0)

__device__ __forceinline__ short f2bf(float f) {
    union { float f; unsigned u; } c; c.f = f;
    unsigned r = (c.u + 0x7FFFu + ((c.u >> 16) & 1u)) >> 16;   // RNE
    return (short)r;
}
__device__ __forceinline__ float bf2f(short s) {
    union { unsigned u; float f; } c; c.u = ((unsigned)(unsigned short)s) << 16; return c.f;
}
__device__ __forceinline__ bf16x8 pack8(float4 a, float4 b) {
    bf16x8 r;
    r[0] = f2bf(a.x); r[1] = f2bf(a.y); r[2] = f2bf(a.z); r[3] = f2bf(a.w);
    r[4] = f2bf(b.x); r[5] = f2bf(b.y); r[6] = f2bf(b.z); r[7] = f2bf(b.w);
    return r;
}

// ---------------- weight f32 -> bf16 + zero KV/Ksum accumulators ----------------
__global__ __launch_bounds__(256) void kWconv(const float* __restrict__ wq, const float* __restrict__ wk,
                                              const float* __restrict__ wv, const float* __restrict__ wm,
                                              const float* __restrict__ w1, const float* __restrict__ w2,
                                              short* __restrict__ dstws, float* __restrict__ kva,
                                              float* __restrict__ ksum) {
    int blk = blockIdx.x;
    int gid = blk * 256 + threadIdx.x;
    kva[gid] = 0.f;
    if (gid < 2048) ksum[gid] = 0.f;
    const float* src; short* dst;
    if (blk < 32)       { src = wq; dst = dstws;          }
    else if (blk < 64)  { src = wk; dst = dstws + 65536;  blk -= 32; }
    else if (blk < 96)  { src = wv; dst = dstws + 131072; blk -= 64; }
    else if (blk < 128) { src = wm; dst = dstws + 196608; blk -= 96; }
    else if (blk < 192) { src = w1; dst = dstws + 262144; blk -= 128; }
    else                { src = w2; dst = dstws + 393216; blk -= 192; }
    int idx = (blk * 256 + threadIdx.x) * 8;
    float4 f0 = *(const float4*)(src + idx), f1 = *(const float4*)(src + idx + 4);
    *(bf16x8*)(dst + idx) = pack8(f0, f1);
}

// ---------------- kernel A: K/V proj + KV/Ksum atomic accumulation ----------------
// grid 1024 = 8 b x 128 blocks (32 src rows). 512 thr = 8 waves; wave w = head w.
// LDS 36.9KB -> 4 blocks/CU (needs VGPR<=64: body kept lean, NO prefetch -- TLP hides latency).
__global__ __launch_bounds__(512, 4) void kA(const float* __restrict__ src,
                                             const short* __restrict__ wk, const short* __restrict__ wv,
                                             float* __restrict__ kva, float* __restrict__ ksum) {
    __shared__ char lds[36864];  // phase1: xs[32][XSTR] (16.9KB); phase3: per-wave kT/vT 4608B x8
    int t = threadIdx.x, lane = t & 63, w = t >> 6, r16 = lane & 15, g = lane >> 4;
    int b = blockIdx.x >> 7, blk = blockIdx.x & 127;
    const float* S = src + ((size_t)b * SEQ + blk * 32) * DM;
#pragma unroll
    for (int i = 0; i < 2; i++) {
        int chunk = t + i * 512, row = chunk >> 5, c8 = chunk & 31;
        const float* p = S + row * DM + c8 * 8;
        float4 f0 = *(const float4*)p, f1 = *(const float4*)(p + 4);
        *(bf16x8*)(lds + row * XSTR + c8 * 16) = pack8(f0, f1);
    }
    __syncthreads();
    f32x4 zz = {0.f, 0.f, 0.f, 0.f};
    f32x4 ak[2][2], av[2][2];
#pragma unroll
    for (int mi = 0; mi < 2; mi++)
#pragma unroll
        for (int ni = 0; ni < 2; ni++) { ak[mi][ni] = zz; av[mi][ni] = zz; }
    const char* aB0 = lds + r16 * XSTR + g * 16;
    const short* wkB0 = wk + (w * 32 + r16) * DM + g * 8;
    const short* wvB0 = wv + (w * 32 + r16) * DM + g * 8;
#pragma unroll
    for (int kt = 0; kt < 8; kt++) {
        bf16x8 A[2];
#pragma unroll
        for (int mi = 0; mi < 2; mi++)
            A[mi] = *(const bf16x8*)(aB0 + mi * (16 * XSTR) + kt * 64);
#pragma unroll
        for (int ni = 0; ni < 2; ni++) {
            bf16x8 Bk = *(const bf16x8*)(wkB0 + ni * (16 * DM) + kt * 32);
            bf16x8 Bv = *(const bf16x8*)(wvB0 + ni * (16 * DM) + kt * 32);
#pragma unroll
            for (int mi = 0; mi < 2; mi++) {
                ak[mi][ni] = MFMA16(A[mi], Bk, ak[mi][ni]);
                av[mi][ni] = MFMA16(A[mi], Bv, av[mi][ni]);
            }
        }
    }
    __syncthreads();
    // elu(k)+1, ksum partials, per-wave transposed tiles kT/vT [32 feat][32 s], 72B row stride
    char* kT = lds + w * 4608;
    char* vT = kT + 2304;
    float ksp[2] = {0.f, 0.f};
#pragma unroll
    for (int mi = 0; mi < 2; mi++)
#pragma unroll
        for (int ni = 0; ni < 2; ni++)
#pragma unroll
            for (int j = 0; j < 4; j++) {
                float q = ak[mi][ni][j];
                float e = q > 0.f ? q + 1.f : __expf(q);
                ksp[ni] += e;
                int srow = mi * 16 + g * 4 + j, feat = ni * 16 + r16;
                int by = feat * TSTR + srow * 2;
                *(short*)(kT + by) = f2bf(e);
                *(short*)(vT + by) = f2bf(av[mi][ni][j]);
            }
    __syncthreads();
    // KVT[v][d] = sum_s V[s][v] * K[s][d]  (per wave; K-dim = 32 = one MFMA)
    f32x4 kv[2][2];
#pragma unroll
    for (int vi = 0; vi < 2; vi++)
#pragma unroll
        for (int di = 0; di < 2; di++) kv[vi][di] = zz;
    {
        bf16x8 Af[2], Bf[2];
#pragma unroll
        for (int vi = 0; vi < 2; vi++) {
            Af[vi] = *(const bf16x8*)(vT + (vi * 16 + r16) * TSTR + g * 16);
            Bf[vi] = *(const bf16x8*)(kT + (vi * 16 + r16) * TSTR + g * 16);
        }
#pragma unroll
        for (int vi = 0; vi < 2; vi++)
#pragma unroll
            for (int di = 0; di < 2; di++) kv[vi][di] = MFMA16(Af[vi], Bf[di], kv[vi][di]);
    }
    float* kvp = kva + (size_t)(b * 8 + w) * 1024;
#pragma unroll
    for (int vi = 0; vi < 2; vi++)
#pragma unroll
        for (int di = 0; di < 2; di++)
#pragma unroll
            for (int j = 0; j < 4; j++) {
                int v = vi * 16 + g * 4 + j, d = di * 16 + r16;
                atomicAdd(&kvp[v * 32 + d], kv[vi][di][j]);
            }
#pragma unroll
    for (int ni = 0; ni < 2; ni++) {
        ksp[ni] += __shfl_xor(ksp[ni], 16);
        ksp[ni] += __shfl_xor(ksp[ni], 32);
    }
    if (lane < 16) {
#pragma unroll
        for (int ni = 0; ni < 2; ni++)
            atomicAdd(&ksum[(b * 8 + w) * 32 + ni * 16 + lane], ksp[ni]);
    }
}

// ---------------- kernel BC: Q proj + attend + merge + LN1 + MLP + LN2 ----------------
// grid 512 = 8 b x 64 blocks (64 rows). 512 thr = 8 waves. LDS 71KB -> 2 blocks/CU.
// B-fragments double-buffered in registers across kt (target ~96-128 VGPR, free at 2 blk/CU).
__global__ __launch_bounds__(512, 4) void kBC(const float* __restrict__ x,
                                              const short* __restrict__ wq_bf, const short* __restrict__ wm_bf,
                                              const short* __restrict__ w1_bf, const short* __restrict__ w2_bf,
                                              const float* __restrict__ kva, const float* __restrict__ ksum,
                                              const float* __restrict__ g1, const float* __restrict__ b1,
                                              const float* __restrict__ g2, const float* __restrict__ b2,
                                              float* __restrict__ out) {
    __shared__ char lds[72704];
    char* xt = lds;
    char* qa = lds + 33792;
    float* red = (float*)(lds + 67584);
    float* ksl = (float*)(lds + 71680);
    int t = threadIdx.x, lane = t & 63, w = t >> 6, r16 = lane & 15, g = lane >> 4;
    int b = blockIdx.x >> 6, lb = blockIdx.x & 63, l0 = lb * 64;
    const float* xb = x + ((size_t)b * SEQ + l0) * DM;
#pragma unroll
    for (int i = 0; i < 4; i++) {
        int chunk = t + i * 512, row = chunk >> 5, c8 = chunk & 31;
        const float* p = xb + row * DM + c8 * 8;
        float4 f0 = *(const float4*)p, f1 = *(const float4*)(p + 4);
        *(bf16x8*)(xt + row * XSTR + c8 * 16) = pack8(f0, f1);
    }
    if (t < 256) ksl[t] = ksum[b * 256 + t];
    __syncthreads();
    f32x4 zz = {0.f, 0.f, 0.f, 0.f};
    const char* aXB = xt + r16 * XSTR + g * 16;
    const char* aQB = qa + r16 * XSTR + g * 16;
    // ---- Q projection (wave w -> head w's 32 cols), B double-buffered ----
    f32x4 acc[4][2];
#pragma unroll
    for (int mi = 0; mi < 4; mi++)
#pragma unroll
        for (int ni = 0; ni < 2; ni++) acc[mi][ni] = zz;
    {
        const short* wqB = wq_bf + (w * 32 + r16) * DM + g * 8;
        bf16x8 B0 = *(const bf16x8*)(wqB);
        bf16x8 B1 = *(const bf16x8*)(wqB + 16 * DM);
#pragma unroll
        for (int kt = 0; kt < 8; kt++) {
            bf16x8 Bn0 = B0, Bn1 = B1;
            if (kt < 7) {
                Bn0 = *(const bf16x8*)(wqB + (kt + 1) * 32);
                Bn1 = *(const bf16x8*)(wqB + 16 * DM + (kt + 1) * 32);
            }
            bf16x8 A[4];
#pragma unroll
            for (int mi = 0; mi < 4; mi++)
                A[mi] = *(const bf16x8*)(aXB + mi * (16 * XSTR) + kt * 64);
#pragma unroll
            for (int mi = 0; mi < 4; mi++) {
                acc[mi][0] = MFMA16(A[mi], B0, acc[mi][0]);
                acc[mi][1] = MFMA16(A[mi], B1, acc[mi][1]);
            }
            B0 = Bn0; B1 = Bn1;
        }
    }
    // elu+1 and Z denominators
    float ks0 = ksl[w * 32 + r16], ks1 = ksl[w * 32 + 16 + r16];
    float Zr[4][4];
#pragma unroll
    for (int mi = 0; mi < 4; mi++)
#pragma unroll
        for (int j = 0; j < 4; j++) {
#pragma unroll
            for (int ni = 0; ni < 2; ni++) {
                float q = acc[mi][ni][j];
                acc[mi][ni][j] = q > 0.f ? q + 1.f : __expf(q);
            }
            float d0 = acc[mi][0][j] * ks0 + acc[mi][1][j] * ks1;
#pragma unroll
            for (int m = 1; m < 16; m <<= 1) d0 += __shfl_xor(d0, m);
            Zr[mi][j] = 1.f / (d0 + 1e-6f);
        }
    // write Q (wave-private cols)
#pragma unroll
    for (int mi = 0; mi < 4; mi++)
#pragma unroll
        for (int ni = 0; ni < 2; ni++)
#pragma unroll
            for (int j = 0; j < 4; j++) {
                int row = mi * 16 + g * 4 + j, col = w * 32 + ni * 16 + r16;
                *(short*)(qa + row * XSTR + col * 2) = f2bf(acc[mi][ni][j]);
            }
    // ---- attend (wave-private cols, K-dim=32); KV frags packed inline from f32 ----
    f32x4 at[4][2];
#pragma unroll
    for (int mi = 0; mi < 4; mi++)
#pragma unroll
        for (int vi = 0; vi < 2; vi++) at[mi][vi] = zz;
    {
        bf16x8 A2[4], B2[2];
#pragma unroll
        for (int mi = 0; mi < 4; mi++)
            A2[mi] = *(const bf16x8*)(qa + (mi * 16 + r16) * XSTR + (w * 32 + g * 8) * 2);
        const float* kvb = kva + (size_t)(b * 8 + w) * 1024;
#pragma unroll
        for (int vi = 0; vi < 2; vi++) {
            const float* p = kvb + (vi * 16 + r16) * 32 + g * 8;
            float4 f0 = *(const float4*)p, f1 = *(const float4*)(p + 4);
            B2[vi] = pack8(f0, f1);
        }
#pragma unroll
        for (int mi = 0; mi < 4; mi++)
#pragma unroll
            for (int vi = 0; vi < 2; vi++) at[mi][vi] = MFMA16(A2[mi], B2[vi], at[mi][vi]);
    }
    // scale by Z, overwrite qa with attended
#pragma unroll
    for (int mi = 0; mi < 4; mi++)
#pragma unroll
        for (int vi = 0; vi < 2; vi++)
#pragma unroll
            for (int j = 0; j < 4; j++) {
                int row = mi * 16 + g * 4 + j, col = w * 32 + vi * 16 + r16;
                *(short*)(qa + row * XSTR + col * 2) = f2bf(at[mi][vi][j] * Zr[mi][j]);
            }
    __syncthreads();
    // ---- merge GEMM, B double-buffered ----
    f32x4 am[4][2];
#pragma unroll
    for (int mi = 0; mi < 4; mi++)
#pragma unroll
        for (int ni = 0; ni < 2; ni++) am[mi][ni] = zz;
    {
        const short* wmB = wm_bf + (w * 32 + r16) * DM + g * 8;
        bf16x8 B0 = *(const bf16x8*)(wmB);
        bf16x8 B1 = *(const bf16x8*)(wmB + 16 * DM);
#pragma unroll
        for (int kt = 0; kt < 8; kt++) {
            bf16x8 Bn0 = B0, Bn1 = B1;
            if (kt < 7) {
                Bn0 = *(const bf16x8*)(wmB + (kt + 1) * 32);
                Bn1 = *(const bf16x8*)(wmB + 16 * DM + (kt + 1) * 32);
            }
            bf16x8 A[4];
#pragma unroll
            for (int mi = 0; mi < 4; mi++)
                A[mi] = *(const bf16x8*)(aQB + mi * (16 * XSTR) + kt * 64);
#pragma unroll
            for (int mi = 0; mi < 4; mi++) {
                am[mi][0] = MFMA16(A[mi], B0, am[mi][0]);
                am[mi][1] = MFMA16(A[mi], B1, am[mi][1]);
            }
            B0 = Bn0; B1 = Bn1;
        }
    }
    // LN1 partials
#pragma unroll
    for (int mi = 0; mi < 4; mi++)
#pragma unroll
        for (int j = 0; j < 4; j++) {
            float s = am[mi][0][j] + am[mi][1][j];
            float s2 = am[mi][0][j] * am[mi][0][j] + am[mi][1][j] * am[mi][1][j];
#pragma unroll
            for (int m = 1; m < 16; m <<= 1) { s += __shfl_xor(s, m); s2 += __shfl_xor(s2, m); }
            if (r16 == 0) { int row = mi * 16 + g * 4 + j; red[(row * 8 + w) * 2] = s; red[(row * 8 + w) * 2 + 1] = s2; }
        }
    __syncthreads();
    // x1 = x + LN1(message), in place in xt
    {
        float g1v[2], b1v[2];
#pragma unroll
        for (int ni = 0; ni < 2; ni++) { int col = w * 32 + ni * 16 + r16; g1v[ni] = g1[col]; b1v[ni] = b1[col]; }
#pragma unroll
        for (int mi = 0; mi < 4; mi++)
#pragma unroll
            for (int j = 0; j < 4; j++) {
                int row = mi * 16 + g * 4 + j;
                float mu = 0.f, ex2 = 0.f;
#pragma unroll
                for (int ww = 0; ww < 8; ww++) { mu += red[(row * 8 + ww) * 2]; ex2 += red[(row * 8 + ww) * 2 + 1]; }
                mu *= (1.f / DM); ex2 *= (1.f / DM);
                float rstd = rsqrtf(ex2 - mu * mu + 1e-5f);
#pragma unroll
                for (int ni = 0; ni < 2; ni++) {
                    int col = w * 32 + ni * 16 + r16;
                    char* bp = xt + row * XSTR + col * 2;
                    float xv = bf2f(*(const short*)bp);
                    *(short*)bp = f2bf(xv + (am[mi][ni][j] - mu) * rstd * g1v[ni] + b1v[ni]);
                }
            }
    }
    __syncthreads();
    // ---- MLP fused in 2 halves of h, B double-buffered ----
    f32x4 a2[4][2];
#pragma unroll
    for (int mi = 0; mi < 4; mi++)
#pragma unroll
        for (int ni = 0; ni < 2; ni++) a2[mi][ni] = zz;
#pragma unroll
    for (int hf = 0; hf < 2; hf++) {
        f32x4 a1[4][2];
#pragma unroll
        for (int mi = 0; mi < 4; mi++)
#pragma unroll
            for (int ni = 0; ni < 2; ni++) a1[mi][ni] = zz;
        {
            const short* w1B = w1_bf + (hf * 256 + w * 32 + r16) * DM + g * 8;
            bf16x8 B0 = *(const bf16x8*)(w1B);
            bf16x8 B1 = *(const bf16x8*)(w1B + 16 * DM);
#pragma unroll
            for (int kt = 0; kt < 8; kt++) {
                bf16x8 Bn0 = B0, Bn1 = B1;
                if (kt < 7) {
                    Bn0 = *(const bf16x8*)(w1B + (kt + 1) * 32);
                    Bn1 = *(const bf16x8*)(w1B + 16 * DM + (kt + 1) * 32);
                }
                bf16x8 A[4];
#pragma unroll
                for (int mi = 0; mi < 4; mi++)
                    A[mi] = *(const bf16x8*)(aXB + mi * (16 * XSTR) + kt * 64);
#pragma unroll
                for (int mi = 0; mi < 4; mi++) {
                    a1[mi][0] = MFMA16(A[mi], B0, a1[mi][0]);
                    a1[mi][1] = MFMA16(A[mi], B1, a1[mi][1]);
                }
                B0 = Bn0; B1 = Bn1;
            }
        }
#pragma unroll
        for (int mi = 0; mi < 4; mi++)
#pragma unroll
            for (int ni = 0; ni < 2; ni++)
#pragma unroll
                for (int j = 0; j < 4; j++) {
                    float hv = a1[mi][ni][j]; hv = hv > 0.f ? hv : 0.f;
                    int row = mi * 16 + g * 4 + j, col = w * 32 + ni * 16 + r16;
                    *(short*)(qa + row * XSTR + col * 2) = f2bf(hv);
                }
        __syncthreads();
        {
            const short* w2B = w2_bf + (w * 32 + r16) * 512 + hf * 256 + g * 8;
            bf16x8 B0 = *(const bf16x8*)(w2B);
            bf16x8 B1 = *(const bf16x8*)(w2B + 16 * 512);
#pragma unroll
            for (int kt = 0; kt < 8; kt++) {
                bf16x8 Bn0 = B0, Bn1 = B1;
                if (kt < 7) {
                    Bn0 = *(const bf16x8*)(w2B + (kt + 1) * 32);
                    Bn1 = *(const bf16x8*)(w2B + 16 * 512 + (kt + 1) * 32);
                }
                bf16x8 A[4];
#pragma unroll
                for (int mi = 0; mi < 4; mi++)
                    A[mi] = *(const bf16x8*)(aQB + mi * (16 * XSTR) + kt * 64);
#pragma unroll
                for (int mi = 0; mi < 4; mi++) {
                    a2[mi][0] = MFMA16(A[mi], B0, a2[mi][0]);
                    a2[mi][1] = MFMA16(A[mi], B1, a2[mi][1]);
                }
                B0 = Bn0; B1 = Bn1;
            }
        }
        __syncthreads();
    }
    // LN2 partials
#pragma unroll
    for (int mi = 0; mi < 4; mi++)
#pragma unroll
        for (int j = 0; j < 4; j++) {
            float s = a2[mi][0][j] + a2[mi][1][j];
            float s2 = a2[mi][0][j] * a2[mi][0][j] + a2[mi][1][j] * a2[mi][1][j];
#pragma unroll
            for (int m = 1; m < 16; m <<= 1) { s += __shfl_xor(s, m); s2 += __shfl_xor(s2, m); }
            if (r16 == 0) { int row = mi * 16 + g * 4 + j; red[(row * 8 + w) * 2] = s; red[(row * 8 + w) * 2 + 1] = s2; }
        }
    __syncthreads();
    // out = x1 + LN2(y)
    {
        float g2v[2], b2v[2];
#pragma unroll
        for (int ni = 0; ni < 2; ni++) { int col = w * 32 + ni * 16 + r16; g2v[ni] = g2[col]; b2v[ni] = b2[col]; }
        float* op = out + ((size_t)b * SEQ + l0) * DM;
#pragma unroll
        for (int mi = 0; mi < 4; mi++)
#pragma unroll
            for (int j = 0; j < 4; j++) {
                int row = mi * 16 + g * 4 + j;
                float mu = 0.f, ex2 = 0.f;
#pragma unroll
                for (int ww = 0; ww < 8; ww++) { mu += red[(row * 8 + ww) * 2]; ex2 += red[(row * 8 + ww) * 2 + 1]; }
                mu *= (1.f / DM); ex2 *= (1.f / DM);
                float rstd = rsqrtf(ex2 - mu * mu + 1e-5f);
#pragma unroll
                for (int ni = 0; ni < 2; ni++) {
                    int col = w * 32 + ni * 16 + r16;
                    float xv = bf2f(*(const short*)(xt + row * XSTR + col * 2));
                    op[row * DM + col] = xv + (a2[mi][ni][j] - mu) * rstd * g2v[ni] + b2v[ni];
                }
            }
    }
}

extern "C" void kernel_launch(void* const* d_in, const int* in_sizes, int n_in,
                              void* d_out, int out_size, void* d_ws, size_t ws_size,
                              hipStream_t stream) {
    const float* x   = (const float*)d_in[0];
    const float* src = (const float*)d_in[1];
    const float* wq  = (const float*)d_in[2];
    const float* wk  = (const float*)d_in[3];
    const float* wv  = (const float*)d_in[4];
    const float* wm  = (const float*)d_in[5];
    const float* w1  = (const float*)d_in[6];
    const float* w2  = (const float*)d_in[7];
    const float* g1  = (const float*)d_in[8];
    const float* b1  = (const float*)d_in[9];
    const float* g2  = (const float*)d_in[10];
    const float* b2  = (const float*)d_in[11];
    float* out = (float*)d_out;

    char* ws = (char*)d_ws;
    short* w_bf = (short*)ws;                  // 1,048,576 B
    float* kva  = (float*)(ws + 1048576);      //   262,144 B (f32 KV accum, zeroed by kWconv)
    float* ksum = (float*)(ws + 1310720);      //     8,192 B

    kWconv<<<256, 256, 0, stream>>>(wq, wk, wv, wm, w1, w2, w_bf, kva, ksum);
    kA<<<1024, 512, 0, stream>>>(src, w_bf + 65536, w_bf + 131072, kva, ksum);
    kBC<<<512, 512, 0, stream>>>(x, w_bf, w_bf + 196608, w_bf + 262144, w_bf + 393216,
                                 kva, ksum, g1, b1, g2, b2, out);
}

// Round 11
// 235.330 us; speedup vs baseline: 1.0322x; 1.0322x over previous
//
#include <hip/hip_runtime.h>

#define DM 256
#define SEQ 4096
#define XSTR 528   // x/qa row stride bytes (132 dwords, 4-bank rotate/row; 2-way residual = free)
#define KSTR 144   // kA transpose tile row stride bytes (36 dwords, 4-bank rotate)

typedef __attribute__((ext_vector_type(8))) short bf16x8;
typedef __attribute__((ext_vector_type(4))) float f32x4;

#define MFMA16(a, b, c) __builtin_amdgcn_mfma_f32_16x16x32_bf16(a, b, c, 0, 0, 0)

__device__ __forceinline__ short f2bf(float f) {
    union { float f; unsigned u; } c; c.f = f;
    unsigned r = (c.u + 0x7FFFu + ((c.u >> 16) & 1u)) >> 16;   // RNE
    return (short)r;
}
__device__ __forceinline__ float bf2f(short s) {
    union { unsigned u; float f; } c; c.u = ((unsigned)(unsigned short)s) << 16; return c.f;
}
__device__ __forceinline__ bf16x8 pack8(float4 a, float4 b) {
    bf16x8 r;
    r[0] = f2bf(a.x); r[1] = f2bf(a.y); r[2] = f2bf(a.z); r[3] = f2bf(a.w);
    r[4] = f2bf(b.x); r[5] = f2bf(b.y); r[6] = f2bf(b.z); r[7] = f2bf(b.w);
    return r;
}

// ---------------- kernel A: K/V proj + KV/Ksum atomic accumulation ----------------
// grid 512 = 8 b x 64 blocks (64 src rows). 512 thr = 8 waves; wave w = head w.
// Prologue: converts kBC's weights (wq|wm|w1|w2 -> w_bf, 768 f32/block) -- kBC runs after kA,
// so visibility is guaranteed. wk/wv are consumed as f32 with inline bf16 pack (L2-resident).
// LDS 73.7KB; atomics at grid 512 = 4.2M (R10's grid-1024 doubled this -> +27us, reverted).
__global__ __launch_bounds__(512, 4) void kA(const float* __restrict__ src,
                                             const float* __restrict__ wk, const float* __restrict__ wv,
                                             const float* __restrict__ wq, const float* __restrict__ wm,
                                             const float* __restrict__ w1, const float* __restrict__ w2,
                                             short* __restrict__ w_bf,
                                             float* __restrict__ kva, float* __restrict__ ksum) {
    __shared__ char lds[73728];
    int t = threadIdx.x, lane = t & 63, w = t >> 6, r16 = lane & 15, g = lane >> 4;
    int b = blockIdx.x >> 6, blk = blockIdx.x & 63;
    // ---- weight conversion slice for kBC: 768 f32 per block of [wq|wm|w1|w2] ----
    {
        int base = blockIdx.x * 768;
#pragma unroll
        for (int i = 0; i < 2; i++) {
            int idx = base + t + i * 512;
            if (t + i * 512 < 768) {
                float v;
                if (idx < 65536)       v = wq[idx];
                else if (idx < 131072) v = wm[idx - 65536];
                else if (idx < 262144) v = w1[idx - 131072];
                else                   v = w2[idx - 262144];
                w_bf[idx] = f2bf(v);
            }
        }
    }
    const float* S = src + ((size_t)b * SEQ + blk * 64) * DM;
#pragma unroll
    for (int i = 0; i < 4; i++) {
        int chunk = t + i * 512, row = chunk >> 5, c8 = chunk & 31;
        const float* p = S + row * DM + c8 * 8;
        float4 f0 = *(const float4*)p, f1 = *(const float4*)(p + 4);
        *(bf16x8*)(lds + row * XSTR + c8 * 16) = pack8(f0, f1);
    }
    __syncthreads();
    f32x4 zz = {0.f, 0.f, 0.f, 0.f};
    f32x4 ak[4][2], av[4][2];
#pragma unroll
    for (int mi = 0; mi < 4; mi++)
#pragma unroll
        for (int ni = 0; ni < 2; ni++) { ak[mi][ni] = zz; av[mi][ni] = zz; }
    const char* aB0 = lds + r16 * XSTR + g * 16;
    const float* wkB0 = wk + (w * 32 + r16) * DM + g * 8;
    const float* wvB0 = wv + (w * 32 + r16) * DM + g * 8;
#pragma unroll
    for (int kt = 0; kt < 8; kt++) {
        bf16x8 A[4];
#pragma unroll
        for (int mi = 0; mi < 4; mi++)
            A[mi] = *(const bf16x8*)(aB0 + mi * (16 * XSTR) + kt * 64);
#pragma unroll
        for (int ni = 0; ni < 2; ni++) {
            const float* pk = wkB0 + ni * (16 * DM) + kt * 32;
            const float* pv = wvB0 + ni * (16 * DM) + kt * 32;
            bf16x8 Bk = pack8(*(const float4*)pk, *(const float4*)(pk + 4));
            bf16x8 Bv = pack8(*(const float4*)pv, *(const float4*)(pv + 4));
#pragma unroll
            for (int mi = 0; mi < 4; mi++) {
                ak[mi][ni] = MFMA16(A[mi], Bk, ak[mi][ni]);
                av[mi][ni] = MFMA16(A[mi], Bv, av[mi][ni]);
            }
        }
    }
    __syncthreads();   // xs reads done before kT/vT overwrite
    // elu(k)+1, ksum partials, per-wave transposed tiles kT/vT [32 feat][64 s]
    char* kT = lds + w * 9216;
    char* vT = kT + 4608;
    float ksp[2] = {0.f, 0.f};
#pragma unroll
    for (int mi = 0; mi < 4; mi++)
#pragma unroll
        for (int ni = 0; ni < 2; ni++)
#pragma unroll
            for (int j = 0; j < 4; j++) {
                float q = ak[mi][ni][j];
                float e = q > 0.f ? q + 1.f : __expf(q);
                ksp[ni] += e;
                int srow = mi * 16 + g * 4 + j, feat = ni * 16 + r16;
                int by = feat * KSTR + srow * 2;
                *(short*)(kT + by) = f2bf(e);
                *(short*)(vT + by) = f2bf(av[mi][ni][j]);
            }
    __syncthreads();
    // KVT[v][d] = sum_s V[s][v] * K[s][d]  (per wave, own head; K-dim = 64 = 2 MFMA steps)
    f32x4 kv[2][2];
#pragma unroll
    for (int vi = 0; vi < 2; vi++)
#pragma unroll
        for (int di = 0; di < 2; di++) kv[vi][di] = zz;
    {
        const char* vB = vT + r16 * KSTR + g * 16;
        const char* kB = kT + r16 * KSTR + g * 16;
#pragma unroll
        for (int st = 0; st < 2; st++) {
            bf16x8 Af[2], Bf[2];
#pragma unroll
            for (int vi = 0; vi < 2; vi++) {
                Af[vi] = *(const bf16x8*)(vB + vi * (16 * KSTR) + st * 64);
                Bf[vi] = *(const bf16x8*)(kB + vi * (16 * KSTR) + st * 64);
            }
#pragma unroll
            for (int vi = 0; vi < 2; vi++)
#pragma unroll
                for (int di = 0; di < 2; di++) kv[vi][di] = MFMA16(Af[vi], Bf[di], kv[vi][di]);
        }
    }
    float* kvp = kva + (size_t)(b * 8 + w) * 1024;
#pragma unroll
    for (int vi = 0; vi < 2; vi++)
#pragma unroll
        for (int di = 0; di < 2; di++)
#pragma unroll
            for (int j = 0; j < 4; j++) {
                int v = vi * 16 + g * 4 + j, d = di * 16 + r16;
                atomicAdd(&kvp[v * 32 + d], kv[vi][di][j]);
            }
#pragma unroll
    for (int ni = 0; ni < 2; ni++) {
        ksp[ni] += __shfl_xor(ksp[ni], 16);
        ksp[ni] += __shfl_xor(ksp[ni], 32);
    }
    if (lane < 16) {
#pragma unroll
        for (int ni = 0; ni < 2; ni++)
            atomicAdd(&ksum[(b * 8 + w) * 32 + ni * 16 + lane], ksp[ni]);
    }
}

// ---------------- kernel BC: Q proj + attend + merge + LN1 + MLP + LN2 ----------------
// grid 512 = 8 b x 64 blocks (64 rows). 512 thr = 8 waves. LDS 71KB -> 2 blocks/CU.
// R7 body (best measured 85us); R8's manual reg-dbuf removed (compiler defeated it, VGPR stayed 64).
__global__ __launch_bounds__(512, 4) void kBC(const float* __restrict__ x,
                                              const short* __restrict__ wq_bf, const short* __restrict__ wm_bf,
                                              const short* __restrict__ w1_bf, const short* __restrict__ w2_bf,
                                              const float* __restrict__ kva, const float* __restrict__ ksum,
                                              const float* __restrict__ g1, const float* __restrict__ b1,
                                              const float* __restrict__ g2, const float* __restrict__ b2,
                                              float* __restrict__ out) {
    __shared__ char lds[72704];
    char* xt = lds;
    char* qa = lds + 33792;
    float* red = (float*)(lds + 67584);
    float* ksl = (float*)(lds + 71680);
    int t = threadIdx.x, lane = t & 63, w = t >> 6, r16 = lane & 15, g = lane >> 4;
    int b = blockIdx.x >> 6, lb = blockIdx.x & 63, l0 = lb * 64;
    const float* xb = x + ((size_t)b * SEQ + l0) * DM;
#pragma unroll
    for (int i = 0; i < 4; i++) {
        int chunk = t + i * 512, row = chunk >> 5, c8 = chunk & 31;
        const float* p = xb + row * DM + c8 * 8;
        float4 f0 = *(const float4*)p, f1 = *(const float4*)(p + 4);
        *(bf16x8*)(xt + row * XSTR + c8 * 16) = pack8(f0, f1);
    }
    if (t < 256) ksl[t] = ksum[b * 256 + t];
    __syncthreads();
    f32x4 zz = {0.f, 0.f, 0.f, 0.f};
    const char* aXB = xt + r16 * XSTR + g * 16;
    const char* aQB = qa + r16 * XSTR + g * 16;
    // ---- Q projection (wave w -> head w's 32 cols) ----
    f32x4 acc[4][2];
#pragma unroll
    for (int mi = 0; mi < 4; mi++)
#pragma unroll
        for (int ni = 0; ni < 2; ni++) acc[mi][ni] = zz;
    {
        const short* wqB = wq_bf + (w * 32 + r16) * DM + g * 8;
#pragma unroll
        for (int kt = 0; kt < 8; kt++) {
            bf16x8 A[4], Bf[2];
#pragma unroll
            for (int mi = 0; mi < 4; mi++)
                A[mi] = *(const bf16x8*)(aXB + mi * (16 * XSTR) + kt * 64);
#pragma unroll
            for (int ni = 0; ni < 2; ni++)
                Bf[ni] = *(const bf16x8*)(wqB + ni * (16 * DM) + kt * 32);
#pragma unroll
            for (int mi = 0; mi < 4; mi++)
#pragma unroll
                for (int ni = 0; ni < 2; ni++) acc[mi][ni] = MFMA16(A[mi], Bf[ni], acc[mi][ni]);
        }
    }
    // elu+1 and Z denominators
    float ks0 = ksl[w * 32 + r16], ks1 = ksl[w * 32 + 16 + r16];
    float Zr[4][4];
#pragma unroll
    for (int mi = 0; mi < 4; mi++)
#pragma unroll
        for (int j = 0; j < 4; j++) {
#pragma unroll
            for (int ni = 0; ni < 2; ni++) {
                float q = acc[mi][ni][j];
                acc[mi][ni][j] = q > 0.f ? q + 1.f : __expf(q);
            }
            float d0 = acc[mi][0][j] * ks0 + acc[mi][1][j] * ks1;
#pragma unroll
            for (int m = 1; m < 16; m <<= 1) d0 += __shfl_xor(d0, m);
            Zr[mi][j] = 1.f / (d0 + 1e-6f);
        }
    // write Q (wave-private cols)
#pragma unroll
    for (int mi = 0; mi < 4; mi++)
#pragma unroll
        for (int ni = 0; ni < 2; ni++)
#pragma unroll
            for (int j = 0; j < 4; j++) {
                int row = mi * 16 + g * 4 + j, col = w * 32 + ni * 16 + r16;
                *(short*)(qa + row * XSTR + col * 2) = f2bf(acc[mi][ni][j]);
            }
    // ---- attend (wave-private cols, K-dim=32); KV frags packed inline from f32 ----
    f32x4 at[4][2];
#pragma unroll
    for (int mi = 0; mi < 4; mi++)
#pragma unroll
        for (int vi = 0; vi < 2; vi++) at[mi][vi] = zz;
    {
        bf16x8 A2[4], B2[2];
#pragma unroll
        for (int mi = 0; mi < 4; mi++)
            A2[mi] = *(const bf16x8*)(qa + (mi * 16 + r16) * XSTR + (w * 32 + g * 8) * 2);
        const float* kvb = kva + (size_t)(b * 8 + w) * 1024;
#pragma unroll
        for (int vi = 0; vi < 2; vi++) {
            const float* p = kvb + (vi * 16 + r16) * 32 + g * 8;
            float4 f0 = *(const float4*)p, f1 = *(const float4*)(p + 4);
            B2[vi] = pack8(f0, f1);
        }
#pragma unroll
        for (int mi = 0; mi < 4; mi++)
#pragma unroll
            for (int vi = 0; vi < 2; vi++) at[mi][vi] = MFMA16(A2[mi], B2[vi], at[mi][vi]);
    }
    // scale by Z, overwrite qa with attended
#pragma unroll
    for (int mi = 0; mi < 4; mi++)
#pragma unroll
        for (int vi = 0; vi < 2; vi++)
#pragma unroll
            for (int j = 0; j < 4; j++) {
                int row = mi * 16 + g * 4 + j, col = w * 32 + vi * 16 + r16;
                *(short*)(qa + row * XSTR + col * 2) = f2bf(at[mi][vi][j] * Zr[mi][j]);
            }
    __syncthreads();   // merge reads all columns
    // ---- merge GEMM ----
    f32x4 am[4][2];
#pragma unroll
    for (int mi = 0; mi < 4; mi++)
#pragma unroll
        for (int ni = 0; ni < 2; ni++) am[mi][ni] = zz;
    {
        const short* wmB = wm_bf + (w * 32 + r16) * DM + g * 8;
#pragma unroll
        for (int kt = 0; kt < 8; kt++) {
            bf16x8 A[4], Bf[2];
#pragma unroll
            for (int mi = 0; mi < 4; mi++)
                A[mi] = *(const bf16x8*)(aQB + mi * (16 * XSTR) + kt * 64);
#pragma unroll
            for (int ni = 0; ni < 2; ni++)
                Bf[ni] = *(const bf16x8*)(wmB + ni * (16 * DM) + kt * 32);
#pragma unroll
            for (int mi = 0; mi < 4; mi++)
#pragma unroll
                for (int ni = 0; ni < 2; ni++) am[mi][ni] = MFMA16(A[mi], Bf[ni], am[mi][ni]);
        }
    }
    // LN1 partials
#pragma unroll
    for (int mi = 0; mi < 4; mi++)
#pragma unroll
        for (int j = 0; j < 4; j++) {
            float s = am[mi][0][j] + am[mi][1][j];
            float s2 = am[mi][0][j] * am[mi][0][j] + am[mi][1][j] * am[mi][1][j];
#pragma unroll
            for (int m = 1; m < 16; m <<= 1) { s += __shfl_xor(s, m); s2 += __shfl_xor(s2, m); }
            if (r16 == 0) { int row = mi * 16 + g * 4 + j; red[(row * 8 + w) * 2] = s; red[(row * 8 + w) * 2 + 1] = s2; }
        }
    __syncthreads();
    // x1 = x + LN1(message), in place in xt
    {
        float g1v[2], b1v[2];
#pragma unroll
        for (int ni = 0; ni < 2; ni++) { int col = w * 32 + ni * 16 + r16; g1v[ni] = g1[col]; b1v[ni] = b1[col]; }
#pragma unroll
        for (int mi = 0; mi < 4; mi++)
#pragma unroll
            for (int j = 0; j < 4; j++) {
                int row = mi * 16 + g * 4 + j;
                float mu = 0.f, ex2 = 0.f;
#pragma unroll
                for (int ww = 0; ww < 8; ww++) { mu += red[(row * 8 + ww) * 2]; ex2 += red[(row * 8 + ww) * 2 + 1]; }
                mu *= (1.f / DM); ex2 *= (1.f / DM);
                float rstd = rsqrtf(ex2 - mu * mu + 1e-5f);
#pragma unroll
                for (int ni = 0; ni < 2; ni++) {
                    int col = w * 32 + ni * 16 + r16;
                    char* bp = xt + row * XSTR + col * 2;
                    float xv = bf2f(*(const short*)bp);
                    *(short*)bp = f2bf(xv + (am[mi][ni][j] - mu) * rstd * g1v[ni] + b1v[ni]);
                }
            }
    }
    __syncthreads();
    // ---- MLP fused in 2 halves of h (qa reused as [64][256] h-tile) ----
    f32x4 a2[4][2];
#pragma unroll
    for (int mi = 0; mi < 4; mi++)
#pragma unroll
        for (int ni = 0; ni < 2; ni++) a2[mi][ni] = zz;
#pragma unroll
    for (int hf = 0; hf < 2; hf++) {
        f32x4 a1[4][2];
#pragma unroll
        for (int mi = 0; mi < 4; mi++)
#pragma unroll
            for (int ni = 0; ni < 2; ni++) a1[mi][ni] = zz;
        {
            const short* w1B = w1_bf + (hf * 256 + w * 32 + r16) * DM + g * 8;
#pragma unroll
            for (int kt = 0; kt < 8; kt++) {
                bf16x8 A[4], Bf[2];
#pragma unroll
                for (int mi = 0; mi < 4; mi++)
                    A[mi] = *(const bf16x8*)(aXB + mi * (16 * XSTR) + kt * 64);
#pragma unroll
                for (int ni = 0; ni < 2; ni++)
                    Bf[ni] = *(const bf16x8*)(w1B + ni * (16 * DM) + kt * 32);
#pragma unroll
                for (int mi = 0; mi < 4; mi++)
#pragma unroll
                    for (int ni = 0; ni < 2; ni++) a1[mi][ni] = MFMA16(A[mi], Bf[ni], a1[mi][ni]);
            }
        }
#pragma unroll
        for (int mi = 0; mi < 4; mi++)
#pragma unroll
            for (int ni = 0; ni < 2; ni++)
#pragma unroll
                for (int j = 0; j < 4; j++) {
                    float hv = a1[mi][ni][j]; hv = hv > 0.f ? hv : 0.f;
                    int row = mi * 16 + g * 4 + j, col = w * 32 + ni * 16 + r16;
                    *(short*)(qa + row * XSTR + col * 2) = f2bf(hv);
                }
        __syncthreads();
        {
            const short* w2B = w2_bf + (w * 32 + r16) * 512 + hf * 256 + g * 8;
#pragma unroll
            for (int kt = 0; kt < 8; kt++) {
                bf16x8 A[4], Bf[2];
#pragma unroll
                for (int mi = 0; mi < 4; mi++)
                    A[mi] = *(const bf16x8*)(aQB + mi * (16 * XSTR) + kt * 64);
#pragma unroll
                for (int ni = 0; ni < 2; ni++)
                    Bf[ni] = *(const bf16x8*)(w2B + ni * (16 * 512) + kt * 32);
#pragma unroll
                for (int mi = 0; mi < 4; mi++)
#pragma unroll
                    for (int ni = 0; ni < 2; ni++) a2[mi][ni] = MFMA16(A[mi], Bf[ni], a2[mi][ni]);
            }
        }
        __syncthreads();
    }
    // LN2 partials
#pragma unroll
    for (int mi = 0; mi < 4; mi++)
#pragma unroll
        for (int j = 0; j < 4; j++) {
            float s = a2[mi][0][j] + a2[mi][1][j];
            float s2 = a2[mi][0][j] * a2[mi][0][j] + a2[mi][1][j] * a2[mi][1][j];
#pragma unroll
            for (int m = 1; m < 16; m <<= 1) { s += __shfl_xor(s, m); s2 += __shfl_xor(s2, m); }
            if (r16 == 0) { int row = mi * 16 + g * 4 + j; red[(row * 8 + w) * 2] = s; red[(row * 8 + w) * 2 + 1] = s2; }
        }
    __syncthreads();
    // out = x1 + LN2(y)
    {
        float g2v[2], b2v[2];
#pragma unroll
        for (int ni = 0; ni < 2; ni++) { int col = w * 32 + ni * 16 + r16; g2v[ni] = g2[col]; b2v[ni] = b2[col]; }
        float* op = out + ((size_t)b * SEQ + l0) * DM;
#pragma unroll
        for (int mi = 0; mi < 4; mi++)
#pragma unroll
            for (int j = 0; j < 4; j++) {
                int row = mi * 16 + g * 4 + j;
                float mu = 0.f, ex2 = 0.f;
#pragma unroll
                for (int ww = 0; ww < 8; ww++) { mu += red[(row * 8 + ww) * 2]; ex2 += red[(row * 8 + ww) * 2 + 1]; }
                mu *= (1.f / DM); ex2 *= (1.f / DM);
                float rstd = rsqrtf(ex2 - mu * mu + 1e-5f);
#pragma unroll
                for (int ni = 0; ni < 2; ni++) {
                    int col = w * 32 + ni * 16 + r16;
                    float xv = bf2f(*(const short*)(xt + row * XSTR + col * 2));
                    op[row * DM + col] = xv + (a2[mi][ni][j] - mu) * rstd * g2v[ni] + b2v[ni];
                }
            }
    }
}

extern "C" void kernel_launch(void* const* d_in, const int* in_sizes, int n_in,
                              void* d_out, int out_size, void* d_ws, size_t ws_size,
                              hipStream_t stream) {
    const float* x   = (const float*)d_in[0];
    const float* src = (const float*)d_in[1];
    const float* wq  = (const float*)d_in[2];
    const float* wk  = (const float*)d_in[3];
    const float* wv  = (const float*)d_in[4];
    const float* wm  = (const float*)d_in[5];
    const float* w1  = (const float*)d_in[6];
    const float* w2  = (const float*)d_in[7];
    const float* g1  = (const float*)d_in[8];
    const float* b1  = (const float*)d_in[9];
    const float* g2  = (const float*)d_in[10];
    const float* b2  = (const float*)d_in[11];
    float* out = (float*)d_out;

    char* ws = (char*)d_ws;
    short* w_bf = (short*)ws;                  // 786,432 B: wq@0 wm@65536 w1@131072 w2@262144 (shorts)
    float* kva  = (float*)(ws + 786432);       // 262,144 B (f32 KV accum)
    float* ksum = (float*)(ws + 1048576);      //   8,192 B

    hipMemsetAsync(ws + 786432, 0, 270336, stream);   // zero kva + ksum (graph-capturable)
    kA<<<512, 512, 0, stream>>>(src, wk, wv, wq, wm, w1, w2, w_bf, kva, ksum);
    kBC<<<512, 512, 0, stream>>>(x, w_bf, w_bf + 65536, w_bf + 131072, w_bf + 262144,
                                 kva, ksum, g1, b1, g2, b2, out);
}

// Round 12
// 214.886 us; speedup vs baseline: 1.1305x; 1.0951x over previous
//
#include <hip/hip_runtime.h>

#define DM 256
#define SEQ 4096
#define XSTR 528   // x/qa row stride bytes (132 dwords, 4-bank rotate/row; 2-way residual = free)
#define KSTR 144   // kA transpose tile row stride bytes (36 dwords, 4-bank rotate)

typedef __attribute__((ext_vector_type(8))) short bf16x8;
typedef __attribute__((ext_vector_type(4))) float f32x4;

#define MFMA16(a, b, c) __builtin_amdgcn_mfma_f32_16x16x32_bf16(a, b, c, 0, 0, 0)

__device__ __forceinline__ short f2bf(float f) {
    union { float f; unsigned u; } c; c.f = f;
    unsigned r = (c.u + 0x7FFFu + ((c.u >> 16) & 1u)) >> 16;   // RNE
    return (short)r;
}
__device__ __forceinline__ float bf2f(short s) {
    union { unsigned u; float f; } c; c.u = ((unsigned)(unsigned short)s) << 16; return c.f;
}
__device__ __forceinline__ bf16x8 pack8(float4 a, float4 b) {
    bf16x8 r;
    r[0] = f2bf(a.x); r[1] = f2bf(a.y); r[2] = f2bf(a.z); r[3] = f2bf(a.w);
    r[4] = f2bf(b.x); r[5] = f2bf(b.y); r[6] = f2bf(b.z); r[7] = f2bf(b.w);
    return r;
}

// ---------------- weight f32 -> bf16 + zero KV/Ksum accumulators ----------------
__global__ __launch_bounds__(256) void kWconv(const float* __restrict__ wq, const float* __restrict__ wk,
                                              const float* __restrict__ wv, const float* __restrict__ wm,
                                              const float* __restrict__ w1, const float* __restrict__ w2,
                                              short* __restrict__ dstws, float* __restrict__ kva,
                                              float* __restrict__ ksum) {
    int blk = blockIdx.x;
    int gid = blk * 256 + threadIdx.x;
    kva[gid] = 0.f;
    if (gid < 2048) ksum[gid] = 0.f;
    const float* src; short* dst;
    if (blk < 32)       { src = wq; dst = dstws;          }
    else if (blk < 64)  { src = wk; dst = dstws + 65536;  blk -= 32; }
    else if (blk < 96)  { src = wv; dst = dstws + 131072; blk -= 64; }
    else if (blk < 128) { src = wm; dst = dstws + 196608; blk -= 96; }
    else if (blk < 192) { src = w1; dst = dstws + 262144; blk -= 128; }
    else                { src = w2; dst = dstws + 393216; blk -= 192; }
    int idx = (blk * 256 + threadIdx.x) * 8;
    float4 f0 = *(const float4*)(src + idx), f1 = *(const float4*)(src + idx + 4);
    *(bf16x8*)(dst + idx) = pack8(f0, f1);
}

// ---------------- kernel A: K/V proj + KV/Ksum atomic accumulation ----------------
// grid 512 = 8 b x 64 blocks (64 src rows). 512 thr = 8 waves; wave w = head w.
// bf16 weights (R11's f32 inline pack regressed). Barrier between wave-private transpose
// write and KV-GEMM removed (kT/vT per-wave disjoint; lgkmcnt orders same-wave LDS ops).
__global__ __launch_bounds__(512, 4) void kA(const float* __restrict__ src,
                                             const short* __restrict__ wk, const short* __restrict__ wv,
                                             float* __restrict__ kva, float* __restrict__ ksum) {
    __shared__ char lds[73728];
    int t = threadIdx.x, lane = t & 63, w = t >> 6, r16 = lane & 15, g = lane >> 4;
    int b = blockIdx.x >> 6, blk = blockIdx.x & 63;
    const float* S = src + ((size_t)b * SEQ + blk * 64) * DM;
#pragma unroll
    for (int i = 0; i < 4; i++) {
        int chunk = t + i * 512, row = chunk >> 5, c8 = chunk & 31;
        const float* p = S + row * DM + c8 * 8;
        float4 f0 = *(const float4*)p, f1 = *(const float4*)(p + 4);
        *(bf16x8*)(lds + row * XSTR + c8 * 16) = pack8(f0, f1);
    }
    __syncthreads();
    f32x4 zz = {0.f, 0.f, 0.f, 0.f};
    f32x4 ak[4][2], av[4][2];
#pragma unroll
    for (int mi = 0; mi < 4; mi++)
#pragma unroll
        for (int ni = 0; ni < 2; ni++) { ak[mi][ni] = zz; av[mi][ni] = zz; }
    const char* aB0 = lds + r16 * XSTR + g * 16;
    const short* wkB0 = wk + (w * 32 + r16) * DM + g * 8;
    const short* wvB0 = wv + (w * 32 + r16) * DM + g * 8;
    // rolled 2-step pipeline: prefetch next kt's weight frags across the backedge
    bf16x8 Ka0 = *(const bf16x8*)(wkB0);
    bf16x8 Ka1 = *(const bf16x8*)(wkB0 + 16 * DM);
    bf16x8 Va0 = *(const bf16x8*)(wvB0);
    bf16x8 Va1 = *(const bf16x8*)(wvB0 + 16 * DM);
#pragma unroll 1
    for (int kt = 0; kt < 8; kt += 2) {
        bf16x8 Kb0 = *(const bf16x8*)(wkB0 + (kt + 1) * 32);
        bf16x8 Kb1 = *(const bf16x8*)(wkB0 + 16 * DM + (kt + 1) * 32);
        bf16x8 Vb0 = *(const bf16x8*)(wvB0 + (kt + 1) * 32);
        bf16x8 Vb1 = *(const bf16x8*)(wvB0 + 16 * DM + (kt + 1) * 32);
        bf16x8 A[4];
#pragma unroll
        for (int mi = 0; mi < 4; mi++)
            A[mi] = *(const bf16x8*)(aB0 + mi * (16 * XSTR) + kt * 64);
#pragma unroll
        for (int mi = 0; mi < 4; mi++) {
            ak[mi][0] = MFMA16(A[mi], Ka0, ak[mi][0]);
            ak[mi][1] = MFMA16(A[mi], Ka1, ak[mi][1]);
            av[mi][0] = MFMA16(A[mi], Va0, av[mi][0]);
            av[mi][1] = MFMA16(A[mi], Va1, av[mi][1]);
        }
        if (kt + 2 < 8) {
            Ka0 = *(const bf16x8*)(wkB0 + (kt + 2) * 32);
            Ka1 = *(const bf16x8*)(wkB0 + 16 * DM + (kt + 2) * 32);
            Va0 = *(const bf16x8*)(wvB0 + (kt + 2) * 32);
            Va1 = *(const bf16x8*)(wvB0 + 16 * DM + (kt + 2) * 32);
        }
#pragma unroll
        for (int mi = 0; mi < 4; mi++)
            A[mi] = *(const bf16x8*)(aB0 + mi * (16 * XSTR) + kt * 64 + 64);
#pragma unroll
        for (int mi = 0; mi < 4; mi++) {
            ak[mi][0] = MFMA16(A[mi], Kb0, ak[mi][0]);
            ak[mi][1] = MFMA16(A[mi], Kb1, ak[mi][1]);
            av[mi][0] = MFMA16(A[mi], Vb0, av[mi][0]);
            av[mi][1] = MFMA16(A[mi], Vb1, av[mi][1]);
        }
    }
    __syncthreads();   // xs reads done (all waves) before kT/vT overlay overwrite
    // elu(k)+1, ksum partials, per-wave transposed tiles kT/vT [32 feat][64 s]
    char* kT = lds + w * 9216;
    char* vT = kT + 4608;
    float ksp[2] = {0.f, 0.f};
#pragma unroll
    for (int mi = 0; mi < 4; mi++)
#pragma unroll
        for (int ni = 0; ni < 2; ni++)
#pragma unroll
            for (int j = 0; j < 4; j++) {
                float q = ak[mi][ni][j];
                float e = q > 0.f ? q + 1.f : __expf(q);
                ksp[ni] += e;
                int srow = mi * 16 + g * 4 + j, feat = ni * 16 + r16;
                int by = feat * KSTR + srow * 2;
                *(short*)(kT + by) = f2bf(e);
                *(short*)(vT + by) = f2bf(av[mi][ni][j]);
            }
    // NO barrier: kT/vT are wave-private; same-wave LDS RAW ordered by lgkmcnt
    f32x4 kv[2][2];
#pragma unroll
    for (int vi = 0; vi < 2; vi++)
#pragma unroll
        for (int di = 0; di < 2; di++) kv[vi][di] = zz;
    {
        const char* vB = vT + r16 * KSTR + g * 16;
        const char* kB = kT + r16 * KSTR + g * 16;
#pragma unroll
        for (int st = 0; st < 2; st++) {
            bf16x8 Af[2], Bf[2];
#pragma unroll
            for (int vi = 0; vi < 2; vi++) {
                Af[vi] = *(const bf16x8*)(vB + vi * (16 * KSTR) + st * 64);
                Bf[vi] = *(const bf16x8*)(kB + vi * (16 * KSTR) + st * 64);
            }
#pragma unroll
            for (int vi = 0; vi < 2; vi++)
#pragma unroll
                for (int di = 0; di < 2; di++) kv[vi][di] = MFMA16(Af[vi], Bf[di], kv[vi][di]);
        }
    }
    float* kvp = kva + (size_t)(b * 8 + w) * 1024;
#pragma unroll
    for (int vi = 0; vi < 2; vi++)
#pragma unroll
        for (int di = 0; di < 2; di++)
#pragma unroll
            for (int j = 0; j < 4; j++) {
                int v = vi * 16 + g * 4 + j, d = di * 16 + r16;
                atomicAdd(&kvp[v * 32 + d], kv[vi][di][j]);
            }
#pragma unroll
    for (int ni = 0; ni < 2; ni++) {
        ksp[ni] += __shfl_xor(ksp[ni], 16);
        ksp[ni] += __shfl_xor(ksp[ni], 32);
    }
    if (lane < 16) {
#pragma unroll
        for (int ni = 0; ni < 2; ni++)
            atomicAdd(&ksum[(b * 8 + w) * 32 + ni * 16 + lane], ksp[ni]);
    }
}

// ---------------- kernel BC: Q proj + attend + merge + LN1 + MLP + LN2 ----------------
// grid 512 = 8 b x 64 blocks (64 rows). 512 thr = 8 waves. LDS 71KB -> 2 blocks/CU.
// GEMM phases use ROLLED (#pragma unroll 1) 2-step ping-pong B prefetch: cross-iteration
// register liveness forces real prefetch distance the scheduler can't sink (R8/R10's
// unrolled dbuf was compiled away). Falsifier: VGPR must rise above 64.
__global__ __launch_bounds__(512, 4) void kBC(const float* __restrict__ x,
                                              const short* __restrict__ wq_bf, const short* __restrict__ wm_bf,
                                              const short* __restrict__ w1_bf, const short* __restrict__ w2_bf,
                                              const float* __restrict__ kva, const float* __restrict__ ksum,
                                              const float* __restrict__ g1, const float* __restrict__ b1,
                                              const float* __restrict__ g2, const float* __restrict__ b2,
                                              float* __restrict__ out) {
    __shared__ char lds[72704];
    char* xt = lds;
    char* qa = lds + 33792;
    float* red = (float*)(lds + 67584);
    float* ksl = (float*)(lds + 71680);
    int t = threadIdx.x, lane = t & 63, w = t >> 6, r16 = lane & 15, g = lane >> 4;
    int b = blockIdx.x >> 6, lb = blockIdx.x & 63, l0 = lb * 64;
    const float* xb = x + ((size_t)b * SEQ + l0) * DM;
#pragma unroll
    for (int i = 0; i < 4; i++) {
        int chunk = t + i * 512, row = chunk >> 5, c8 = chunk & 31;
        const float* p = xb + row * DM + c8 * 8;
        float4 f0 = *(const float4*)p, f1 = *(const float4*)(p + 4);
        *(bf16x8*)(xt + row * XSTR + c8 * 16) = pack8(f0, f1);
    }
    if (t < 256) ksl[t] = ksum[b * 256 + t];
    __syncthreads();
    f32x4 zz = {0.f, 0.f, 0.f, 0.f};
    const char* aXB = xt + r16 * XSTR + g * 16;
    const char* aQB = qa + r16 * XSTR + g * 16;
    // ---- Q projection: rolled ping-pong pipeline ----
    f32x4 acc[4][2];
#pragma unroll
    for (int mi = 0; mi < 4; mi++)
#pragma unroll
        for (int ni = 0; ni < 2; ni++) acc[mi][ni] = zz;
    {
        const short* wqB = wq_bf + (w * 32 + r16) * DM + g * 8;
        bf16x8 Ba0 = *(const bf16x8*)(wqB);
        bf16x8 Ba1 = *(const bf16x8*)(wqB + 16 * DM);
#pragma unroll 1
        for (int kt = 0; kt < 8; kt += 2) {
            bf16x8 Bb0 = *(const bf16x8*)(wqB + (kt + 1) * 32);
            bf16x8 Bb1 = *(const bf16x8*)(wqB + 16 * DM + (kt + 1) * 32);
            bf16x8 A[4];
#pragma unroll
            for (int mi = 0; mi < 4; mi++)
                A[mi] = *(const bf16x8*)(aXB + mi * (16 * XSTR) + kt * 64);
#pragma unroll
            for (int mi = 0; mi < 4; mi++) {
                acc[mi][0] = MFMA16(A[mi], Ba0, acc[mi][0]);
                acc[mi][1] = MFMA16(A[mi], Ba1, acc[mi][1]);
            }
            if (kt + 2 < 8) {
                Ba0 = *(const bf16x8*)(wqB + (kt + 2) * 32);
                Ba1 = *(const bf16x8*)(wqB + 16 * DM + (kt + 2) * 32);
            }
#pragma unroll
            for (int mi = 0; mi < 4; mi++)
                A[mi] = *(const bf16x8*)(aXB + mi * (16 * XSTR) + kt * 64 + 64);
#pragma unroll
            for (int mi = 0; mi < 4; mi++) {
                acc[mi][0] = MFMA16(A[mi], Bb0, acc[mi][0]);
                acc[mi][1] = MFMA16(A[mi], Bb1, acc[mi][1]);
            }
        }
    }
    // elu+1 and Z denominators
    float ks0 = ksl[w * 32 + r16], ks1 = ksl[w * 32 + 16 + r16];
    float Zr[4][4];
#pragma unroll
    for (int mi = 0; mi < 4; mi++)
#pragma unroll
        for (int j = 0; j < 4; j++) {
#pragma unroll
            for (int ni = 0; ni < 2; ni++) {
                float q = acc[mi][ni][j];
                acc[mi][ni][j] = q > 0.f ? q + 1.f : __expf(q);
            }
            float d0 = acc[mi][0][j] * ks0 + acc[mi][1][j] * ks1;
#pragma unroll
            for (int m = 1; m < 16; m <<= 1) d0 += __shfl_xor(d0, m);
            Zr[mi][j] = 1.f / (d0 + 1e-6f);
        }
    // write Q (wave-private cols)
#pragma unroll
    for (int mi = 0; mi < 4; mi++)
#pragma unroll
        for (int ni = 0; ni < 2; ni++)
#pragma unroll
            for (int j = 0; j < 4; j++) {
                int row = mi * 16 + g * 4 + j, col = w * 32 + ni * 16 + r16;
                *(short*)(qa + row * XSTR + col * 2) = f2bf(acc[mi][ni][j]);
            }
    // ---- attend (wave-private cols, K-dim=32); KV frags packed inline from f32 ----
    f32x4 at[4][2];
#pragma unroll
    for (int mi = 0; mi < 4; mi++)
#pragma unroll
        for (int vi = 0; vi < 2; vi++) at[mi][vi] = zz;
    {
        bf16x8 A2[4], B2[2];
#pragma unroll
        for (int mi = 0; mi < 4; mi++)
            A2[mi] = *(const bf16x8*)(qa + (mi * 16 + r16) * XSTR + (w * 32 + g * 8) * 2);
        const float* kvb = kva + (size_t)(b * 8 + w) * 1024;
#pragma unroll
        for (int vi = 0; vi < 2; vi++) {
            const float* p = kvb + (vi * 16 + r16) * 32 + g * 8;
            float4 f0 = *(const float4*)p, f1 = *(const float4*)(p + 4);
            B2[vi] = pack8(f0, f1);
        }
#pragma unroll
        for (int mi = 0; mi < 4; mi++)
#pragma unroll
            for (int vi = 0; vi < 2; vi++) at[mi][vi] = MFMA16(A2[mi], B2[vi], at[mi][vi]);
    }
    // scale by Z, overwrite qa with attended
#pragma unroll
    for (int mi = 0; mi < 4; mi++)
#pragma unroll
        for (int vi = 0; vi < 2; vi++)
#pragma unroll
            for (int j = 0; j < 4; j++) {
                int row = mi * 16 + g * 4 + j, col = w * 32 + vi * 16 + r16;
                *(short*)(qa + row * XSTR + col * 2) = f2bf(at[mi][vi][j] * Zr[mi][j]);
            }
    __syncthreads();   // merge reads all columns
    // ---- merge GEMM: rolled ping-pong pipeline ----
    f32x4 am[4][2];
#pragma unroll
    for (int mi = 0; mi < 4; mi++)
#pragma unroll
        for (int ni = 0; ni < 2; ni++) am[mi][ni] = zz;
    {
        const short* wmB = wm_bf + (w * 32 + r16) * DM + g * 8;
        bf16x8 Ba0 = *(const bf16x8*)(wmB);
        bf16x8 Ba1 = *(const bf16x8*)(wmB + 16 * DM);
#pragma unroll 1
        for (int kt = 0; kt < 8; kt += 2) {
            bf16x8 Bb0 = *(const bf16x8*)(wmB + (kt + 1) * 32);
            bf16x8 Bb1 = *(const bf16x8*)(wmB + 16 * DM + (kt + 1) * 32);
            bf16x8 A[4];
#pragma unroll
            for (int mi = 0; mi < 4; mi++)
                A[mi] = *(const bf16x8*)(aQB + mi * (16 * XSTR) + kt * 64);
#pragma unroll
            for (int mi = 0; mi < 4; mi++) {
                am[mi][0] = MFMA16(A[mi], Ba0, am[mi][0]);
                am[mi][1] = MFMA16(A[mi], Ba1, am[mi][1]);
            }
            if (kt + 2 < 8) {
                Ba0 = *(const bf16x8*)(wmB + (kt + 2) * 32);
                Ba1 = *(const bf16x8*)(wmB + 16 * DM + (kt + 2) * 32);
            }
#pragma unroll
            for (int mi = 0; mi < 4; mi++)
                A[mi] = *(const bf16x8*)(aQB + mi * (16 * XSTR) + kt * 64 + 64);
#pragma unroll
            for (int mi = 0; mi < 4; mi++) {
                am[mi][0] = MFMA16(A[mi], Bb0, am[mi][0]);
                am[mi][1] = MFMA16(A[mi], Bb1, am[mi][1]);
            }
        }
    }
    // LN1 partials
#pragma unroll
    for (int mi = 0; mi < 4; mi++)
#pragma unroll
        for (int j = 0; j < 4; j++) {
            float s = am[mi][0][j] + am[mi][1][j];
            float s2 = am[mi][0][j] * am[mi][0][j] + am[mi][1][j] * am[mi][1][j];
#pragma unroll
            for (int m = 1; m < 16; m <<= 1) { s += __shfl_xor(s, m); s2 += __shfl_xor(s2, m); }
            if (r16 == 0) { int row = mi * 16 + g * 4 + j; red[(row * 8 + w) * 2] = s; red[(row * 8 + w) * 2 + 1] = s2; }
        }
    __syncthreads();
    // x1 = x + LN1(message), in place in xt
    {
        float g1v[2], b1v[2];
#pragma unroll
        for (int ni = 0; ni < 2; ni++) { int col = w * 32 + ni * 16 + r16; g1v[ni] = g1[col]; b1v[ni] = b1[col]; }
#pragma unroll
        for (int mi = 0; mi < 4; mi++)
#pragma unroll
            for (int j = 0; j < 4; j++) {
                int row = mi * 16 + g * 4 + j;
                float mu = 0.f, ex2 = 0.f;
#pragma unroll
                for (int ww = 0; ww < 8; ww++) { mu += red[(row * 8 + ww) * 2]; ex2 += red[(row * 8 + ww) * 2 + 1]; }
                mu *= (1.f / DM); ex2 *= (1.f / DM);
                float rstd = rsqrtf(ex2 - mu * mu + 1e-5f);
#pragma unroll
                for (int ni = 0; ni < 2; ni++) {
                    int col = w * 32 + ni * 16 + r16;
                    char* bp = xt + row * XSTR + col * 2;
                    float xv = bf2f(*(const short*)bp);
                    *(short*)bp = f2bf(xv + (am[mi][ni][j] - mu) * rstd * g1v[ni] + b1v[ni]);
                }
            }
    }
    __syncthreads();
    // ---- MLP fused in 2 halves of h, rolled ping-pong pipelines ----
    f32x4 a2[4][2];
#pragma unroll
    for (int mi = 0; mi < 4; mi++)
#pragma unroll
        for (int ni = 0; ni < 2; ni++) a2[mi][ni] = zz;
#pragma unroll
    for (int hf = 0; hf < 2; hf++) {
        f32x4 a1[4][2];
#pragma unroll
        for (int mi = 0; mi < 4; mi++)
#pragma unroll
            for (int ni = 0; ni < 2; ni++) a1[mi][ni] = zz;
        {
            const short* w1B = w1_bf + (hf * 256 + w * 32 + r16) * DM + g * 8;
            bf16x8 Ba0 = *(const bf16x8*)(w1B);
            bf16x8 Ba1 = *(const bf16x8*)(w1B + 16 * DM);
#pragma unroll 1
            for (int kt = 0; kt < 8; kt += 2) {
                bf16x8 Bb0 = *(const bf16x8*)(w1B + (kt + 1) * 32);
                bf16x8 Bb1 = *(const bf16x8*)(w1B + 16 * DM + (kt + 1) * 32);
                bf16x8 A[4];
#pragma unroll
                for (int mi = 0; mi < 4; mi++)
                    A[mi] = *(const bf16x8*)(aXB + mi * (16 * XSTR) + kt * 64);
#pragma unroll
                for (int mi = 0; mi < 4; mi++) {
                    a1[mi][0] = MFMA16(A[mi], Ba0, a1[mi][0]);
                    a1[mi][1] = MFMA16(A[mi], Ba1, a1[mi][1]);
                }
                if (kt + 2 < 8) {
                    Ba0 = *(const bf16x8*)(w1B + (kt + 2) * 32);
                    Ba1 = *(const bf16x8*)(w1B + 16 * DM + (kt + 2) * 32);
                }
#pragma unroll
                for (int mi = 0; mi < 4; mi++)
                    A[mi] = *(const bf16x8*)(aXB + mi * (16 * XSTR) + kt * 64 + 64);
#pragma unroll
                for (int mi = 0; mi < 4; mi++) {
                    a1[mi][0] = MFMA16(A[mi], Bb0, a1[mi][0]);
                    a1[mi][1] = MFMA16(A[mi], Bb1, a1[mi][1]);
                }
            }
        }
#pragma unroll
        for (int mi = 0; mi < 4; mi++)
#pragma unroll
            for (int ni = 0; ni < 2; ni++)
#pragma unroll
                for (int j = 0; j < 4; j++) {
                    float hv = a1[mi][ni][j]; hv = hv > 0.f ? hv : 0.f;
                    int row = mi * 16 + g * 4 + j, col = w * 32 + ni * 16 + r16;
                    *(short*)(qa + row * XSTR + col * 2) = f2bf(hv);
                }
        __syncthreads();
        {
            const short* w2B = w2_bf + (w * 32 + r16) * 512 + hf * 256 + g * 8;
            bf16x8 Ba0 = *(const bf16x8*)(w2B);
            bf16x8 Ba1 = *(const bf16x8*)(w2B + 16 * 512);
#pragma unroll 1
            for (int kt = 0; kt < 8; kt += 2) {
                bf16x8 Bb0 = *(const bf16x8*)(w2B + (kt + 1) * 32);
                bf16x8 Bb1 = *(const bf16x8*)(w2B + 16 * 512 + (kt + 1) * 32);
                bf16x8 A[4];
#pragma unroll
                for (int mi = 0; mi < 4; mi++)
                    A[mi] = *(const bf16x8*)(aQB + mi * (16 * XSTR) + kt * 64);
#pragma unroll
                for (int mi = 0; mi < 4; mi++) {
                    a2[mi][0] = MFMA16(A[mi], Ba0, a2[mi][0]);
                    a2[mi][1] = MFMA16(A[mi], Ba1, a2[mi][1]);
                }
                if (kt + 2 < 8) {
                    Ba0 = *(const bf16x8*)(w2B + (kt + 2) * 32);
                    Ba1 = *(const bf16x8*)(w2B + 16 * 512 + (kt + 2) * 32);
                }
#pragma unroll
                for (int mi = 0; mi < 4; mi++)
                    A[mi] = *(const bf16x8*)(aQB + mi * (16 * XSTR) + kt * 64 + 64);
#pragma unroll
                for (int mi = 0; mi < 4; mi++) {
                    a2[mi][0] = MFMA16(A[mi], Bb0, a2[mi][0]);
                    a2[mi][1] = MFMA16(A[mi], Bb1, a2[mi][1]);
                }
            }
        }
        __syncthreads();
    }
    // LN2 partials
#pragma unroll
    for (int mi = 0; mi < 4; mi++)
#pragma unroll
        for (int j = 0; j < 4; j++) {
            float s = a2[mi][0][j] + a2[mi][1][j];
            float s2 = a2[mi][0][j] * a2[mi][0][j] + a2[mi][1][j] * a2[mi][1][j];
#pragma unroll
            for (int m = 1; m < 16; m <<= 1) { s += __shfl_xor(s, m); s2 += __shfl_xor(s2, m); }
            if (r16 == 0) { int row = mi * 16 + g * 4 + j; red[(row * 8 + w) * 2] = s; red[(row * 8 + w) * 2 + 1] = s2; }
        }
    __syncthreads();
    // out = x1 + LN2(y)
    {
        float g2v[2], b2v[2];
#pragma unroll
        for (int ni = 0; ni < 2; ni++) { int col = w * 32 + ni * 16 + r16; g2v[ni] = g2[col]; b2v[ni] = b2[col]; }
        float* op = out + ((size_t)b * SEQ + l0) * DM;
#pragma unroll
        for (int mi = 0; mi < 4; mi++)
#pragma unroll
            for (int j = 0; j < 4; j++) {
                int row = mi * 16 + g * 4 + j;
                float mu = 0.f, ex2 = 0.f;
#pragma unroll
                for (int ww = 0; ww < 8; ww++) { mu += red[(row * 8 + ww) * 2]; ex2 += red[(row * 8 + ww) * 2 + 1]; }
                mu *= (1.f / DM); ex2 *= (1.f / DM);
                float rstd = rsqrtf(ex2 - mu * mu + 1e-5f);
#pragma unroll
                for (int ni = 0; ni < 2; ni++) {
                    int col = w * 32 + ni * 16 + r16;
                    float xv = bf2f(*(const short*)(xt + row * XSTR + col * 2));
                    op[row * DM + col] = xv + (a2[mi][ni][j] - mu) * rstd * g2v[ni] + b2v[ni];
                }
            }
    }
}

extern "C" void kernel_launch(void* const* d_in, const int* in_sizes, int n_in,
                              void* d_out, int out_size, void* d_ws, size_t ws_size,
                              hipStream_t stream) {
    const float* x   = (const float*)d_in[0];
    const float* src = (const float*)d_in[1];
    const float* wq  = (const float*)d_in[2];
    const float* wk  = (const float*)d_in[3];
    const float* wv  = (const float*)d_in[4];
    const float* wm  = (const float*)d_in[5];
    const float* w1  = (const float*)d_in[6];
    const float* w2  = (const float*)d_in[7];
    const float* g1  = (const float*)d_in[8];
    const float* b1  = (const float*)d_in[9];
    const float* g2  = (const float*)d_in[10];
    const float* b2  = (const float*)d_in[11];
    float* out = (float*)d_out;

    char* ws = (char*)d_ws;
    short* w_bf = (short*)ws;                  // 1,048,576 B
    float* kva  = (float*)(ws + 1048576);      //   262,144 B (f32 KV accum, zeroed by kWconv)
    float* ksum = (float*)(ws + 1310720);      //     8,192 B

    kWconv<<<256, 256, 0, stream>>>(wq, wk, wv, wm, w1, w2, w_bf, kva, ksum);
    kA<<<512, 512, 0, stream>>>(src, w_bf + 65536, w_bf + 131072, kva, ksum);
    kBC<<<512, 512, 0, stream>>>(x, w_bf, w_bf + 196608, w_bf + 262144, w_bf + 393216,
                                 kva, ksum, g1, b1, g2, b2, out);
}